// Round 8
// baseline (242.659 us; speedup 1.0000x reference)
//
#include <hip/hip_runtime.h>

// R15: R13b verified base (97.79us) + last-block combine:
//   - attn blocks of a (qt,h) group (8 chunks) count completion via
//     device-scope atomicAdd; the last block combines the 8 partials and
//     writes normalized O f16 (1MB). Overlaps the 8.5MB partial re-read
//     with still-running attn blocks.
//   - out_kernel reads O (1MB) instead of Opart+lpart (8.5MB).
//   - counters zeroed via hipMemsetAsync on the stream (capture-safe).
//
// Workspace (~12.6 MB):
//   qb: [4][4096][32] f16 (pre-scaled by 32^-0.5 * log2e)   1 MB
//   kb: [4][4096][32] f16                                   1 MB
//   vb: [4][32][4096] f16                                   1 MB
//   Opart: [8ck][4h][4096][32] f16                          8 MB
//   O: [4h][4096][32] f16 (normalized)                      1 MB
//   lpart: [8ck][4h][4096] f32                              512 KB
//   cnt: [16qt][4h] u32                                     256 B

typedef _Float16 f16x8 __attribute__((ext_vector_type(8)));
typedef _Float16 f16x4 __attribute__((ext_vector_type(4)));
typedef _Float16 f16x2v __attribute__((ext_vector_type(2)));
typedef __fp16 fp16x2n __attribute__((ext_vector_type(2)));   // builtin's native type
typedef float f32x4 __attribute__((ext_vector_type(4)));

static __device__ inline f16x4 pack4(float a, float b, float c, float d) {
  f16x4 r;
  r.x = (_Float16)a; r.y = (_Float16)b; r.z = (_Float16)c; r.w = (_Float16)d;
  return r;
}
static __device__ inline f16x4 pack4_rtz(float a, float b, float c, float d) {
  fp16x2n lo = __builtin_amdgcn_cvt_pkrtz(a, b);
  fp16x2n hi = __builtin_amdgcn_cvt_pkrtz(c, d);
  f16x4 r;
  r.x = (_Float16)lo.x; r.y = (_Float16)lo.y;
  r.z = (_Float16)hi.x; r.w = (_Float16)hi.y;
  return r;
}
static __device__ inline f16x2v pack2(float a, float b) {
  f16x2v r;
  r.x = (_Float16)a; r.y = (_Float16)b;
  return r;
}

// ---------------- Kernel 1: QKV projection ----------------
__global__ __launch_bounds__(256) void qkv_kernel(
    const float* __restrict__ x, const float* __restrict__ w,
    _Float16* __restrict__ qo, _Float16* __restrict__ ko, _Float16* __restrict__ vo)
{
  __shared__ __align__(16) float xs[64 * 68];
  __shared__ __align__(16) float wsb[32 * 68];
  const int t = threadIdx.x;
  const int n0 = blockIdx.x * 64;
  const int o0 = blockIdx.y * 32;
  #pragma unroll
  for (int i = 0; i < 4; ++i) {
    int ch = t + i * 256;
    int c = ch >> 4, p = ch & 15;
    *reinterpret_cast<float4*>(&xs[c * 68 + p * 4]) =
        *reinterpret_cast<const float4*>(&x[c * 4096 + n0 + p * 4]);
  }
  #pragma unroll
  for (int i = 0; i < 2; ++i) {
    int ch = t + i * 256;
    int o = ch >> 4, p = ch & 15;
    *reinterpret_cast<float4*>(&wsb[o * 68 + p * 4]) =
        *reinterpret_cast<const float4*>(&w[(o0 + o) * 64 + p * 4]);
  }
  __syncthreads();
  const int oL = (t >> 5) * 4;
  const int nL = (t & 31) * 2;
  float acc[4][2] = {};
  for (int c4 = 0; c4 < 64; c4 += 4) {
    float2 xa[4];
    #pragma unroll
    for (int k = 0; k < 4; ++k)
      xa[k] = *reinterpret_cast<const float2*>(&xs[(c4 + k) * 68 + nL]);
    #pragma unroll
    for (int i = 0; i < 4; ++i) {
      float4 wv = *reinterpret_cast<const float4*>(&wsb[(oL + i) * 68 + c4]);
      acc[i][0] += wv.x * xa[0].x + wv.y * xa[1].x + wv.z * xa[2].x + wv.w * xa[3].x;
      acc[i][1] += wv.x * xa[0].y + wv.y * xa[1].y + wv.z * xa[2].y + wv.w * xa[3].y;
    }
  }
  const float qs = 0.17677669529663689f * 1.4426950408889634f;  // 32^-.5 * log2e
  if (o0 < 128) {
    int ho = o0 >> 5;
    #pragma unroll
    for (int j = 0; j < 2; ++j) {
      int n = n0 + nL + j;
      *reinterpret_cast<f16x4*>(&qo[(ho * 4096 + n) * 32 + oL]) =
          pack4(acc[0][j] * qs, acc[1][j] * qs, acc[2][j] * qs, acc[3][j] * qs);
    }
  } else if (o0 < 256) {
    int ho = (o0 - 128) >> 5;
    #pragma unroll
    for (int j = 0; j < 2; ++j) {
      int n = n0 + nL + j;
      *reinterpret_cast<f16x4*>(&ko[(ho * 4096 + n) * 32 + oL]) =
          pack4(acc[0][j], acc[1][j], acc[2][j], acc[3][j]);
    }
  } else {
    #pragma unroll
    for (int i = 0; i < 4; ++i) {
      *reinterpret_cast<f16x2v*>(&vo[(size_t)(o0 - 256 + oL + i) * 4096 + n0 + nL]) =
          pack2(acc[i][0], acc[i][1]);
    }
  }
}

// ---------------- Kernel 2: flash attention + last-block combine ----------------
// grid (8 chunks, 16 qblocks of 256, 4 heads); 8 waves/block, wave owns 32 q.
// Threads 0-255 stage K, threads 256-511 stage V.
__global__ __launch_bounds__(512, 4) void attn_kernel(
    const _Float16* __restrict__ qg, const _Float16* __restrict__ kg,
    const _Float16* __restrict__ vg, _Float16* __restrict__ Opart,
    _Float16* __restrict__ O, float* __restrict__ lpart,
    unsigned int* __restrict__ cnt, int jlen)
{
  __shared__ __align__(16) _Float16 Ks[2][64 * 40];  // [j][d] stride 40
  __shared__ __align__(16) _Float16 Vs[2][32 * 72];  // [d][j] stride 72
  __shared__ int isLast;
  const int t = threadIdx.x;
  const int ck = blockIdx.x;
  const int qt = blockIdx.y;
  const int h  = blockIdx.z;
  const int w = t >> 6;
  const int lane = t & 63;
  const int m = lane & 15;
  const int quad = lane >> 4;
  const int qw = qt * 256 + w * 32;

  // Q fragments (B-operand of S^T): group g covers q = qw + g*16 + m
  f16x8 aq[2];
  #pragma unroll
  for (int g = 0; g < 2; ++g)
    aq[g] = *reinterpret_cast<const f16x8*>(
        &qg[(h * 4096 + qw + g * 16 + m) * 32 + quad * 8]);

  f32x4 acc[2][2];
  #pragma unroll
  for (int g = 0; g < 2; ++g) {
    acc[g][0] = f32x4{0.f, 0.f, 0.f, 0.f};
    acc[g][1] = f32x4{0.f, 0.f, 0.f, 0.f};
  }
  float ls[2] = {0.f, 0.f};

  const int jbeg = ck * jlen;
  const bool isK = (t < 256);
  const _Float16* gp;
  int ldsoff;
  if (isK) {
    int kr = t >> 2, ksg = t & 3;        // K staging: 64 rows x 4 x 16B
    gp = kg + (size_t)(h * 4096 + jbeg + kr) * 32 + ksg * 8;
    ldsoff = kr * 40 + ksg * 8;
  } else {
    int c = t - 256, vr = c >> 3, vsg = c & 7;  // V staging: 32 rows x 8 x 16B
    gp = vg + (size_t)(h * 32 + vr) * 4096 + jbeg + vsg * 8;
    ldsoff = vr * 72 + vsg * 8;
  }

  if (isK)
    *reinterpret_cast<uint4*>(&Ks[0][ldsoff]) = *reinterpret_cast<const uint4*>(gp);
  else
    *reinterpret_cast<uint4*>(&Vs[0][ldsoff]) = *reinterpret_cast<const uint4*>(gp);
  __syncthreads();

  for (int it = 0; it < jlen; it += 64) {
    const int buf = (it >> 6) & 1;
    if (it + 64 < jlen) {
      if (isK)
        *reinterpret_cast<uint4*>(&Ks[buf ^ 1][ldsoff]) =
            *reinterpret_cast<const uint4*>(gp + (size_t)(it + 64) * 32);
      else
        *reinterpret_cast<uint4*>(&Vs[buf ^ 1][ldsoff]) =
            *reinterpret_cast<const uint4*>(gp + (it + 64));
    }
    #pragma unroll
    for (int jt = 0; jt < 4; ++jt) {
      f16x8 kf = *reinterpret_cast<const f16x8*>(&Ks[buf][(jt * 16 + m) * 40 + quad * 8]);
      f16x4 vf0 = *reinterpret_cast<const f16x4*>(&Vs[buf][m * 72 + jt * 16 + quad * 4]);
      f16x4 vf1 = *reinterpret_cast<const f16x4*>(&Vs[buf][(16 + m) * 72 + jt * 16 + quad * 4]);
      f32x4 z = {0.f, 0.f, 0.f, 0.f};
      f32x4 sT[2];
      #pragma unroll
      for (int g = 0; g < 2; ++g)
        sT[g] = __builtin_amdgcn_mfma_f32_16x16x32_f16(kf, aq[g], z, 0, 0, 0);
      #pragma unroll
      for (int g = 0; g < 2; ++g) {
        float p0 = exp2f(sT[g][0]), p1 = exp2f(sT[g][1]);
        float p2 = exp2f(sT[g][2]), p3 = exp2f(sT[g][3]);
        ls[g] += (p0 + p1) + (p2 + p3);
        f16x4 p = pack4_rtz(p0, p1, p2, p3);   // A[m=q][k=quad*4+r]
        acc[g][0] = __builtin_amdgcn_mfma_f32_16x16x16f16(p, vf0, acc[g][0], 0, 0, 0);
        acc[g][1] = __builtin_amdgcn_mfma_f32_16x16x16f16(p, vf1, acc[g][1], 0, 0, 0);
      }
    }
    __syncthreads();
  }

  #pragma unroll
  for (int g = 0; g < 2; ++g) {
    ls[g] += __shfl_xor(ls[g], 16);
    ls[g] += __shfl_xor(ls[g], 32);
  }
  // O partials in f16: C-layout rows q_local = quad*4+r, col d = m
  const size_t cb = (size_t)(ck * 4 + h) * 4096;
  #pragma unroll
  for (int g = 0; g < 2; ++g) {
    #pragma unroll
    for (int dt = 0; dt < 2; ++dt) {
      #pragma unroll
      for (int r = 0; r < 4; ++r) {
        int q = qw + g * 16 + quad * 4 + r;
        Opart[(cb + q) * 32 + dt * 16 + m] = (_Float16)acc[g][dt][r];
      }
    }
  }
  if (quad == 0) {
    #pragma unroll
    for (int g = 0; g < 2; ++g)
      lpart[cb + qw + g * 16 + m] = ls[g];
  }

  // -------- last-block combine for this (qt,h) group --------
  __threadfence();                       // release: partials visible device-wide
  if (t == 0) {
    unsigned int old = atomicAdd(&cnt[qt * 4 + h], 1u);
    isLast = (old == 7u);
  }
  __syncthreads();
  if (isLast) {
    __threadfence();                     // acquire: see all 8 groups' partials
    const int qL = t >> 1;               // 0..255
    const int d0 = (t & 1) * 16;         // 0 or 16
    const int q = qt * 256 + qL;
    float lsum = 0.f;
    #pragma unroll
    for (int c2 = 0; c2 < 8; ++c2)
      lsum += lpart[(size_t)(c2 * 4 + h) * 4096 + q];
    const float inv = 1.f / lsum;
    float s[16];
    #pragma unroll
    for (int i = 0; i < 16; ++i) s[i] = 0.f;
    #pragma unroll
    for (int c2 = 0; c2 < 8; ++c2) {
      const _Float16* src = &Opart[((size_t)(c2 * 4 + h) * 4096 + q) * 32 + d0];
      #pragma unroll
      for (int b4 = 0; b4 < 4; ++b4) {
        f16x4 v4 = *reinterpret_cast<const f16x4*>(src + b4 * 4);
        s[b4 * 4 + 0] += (float)v4.x; s[b4 * 4 + 1] += (float)v4.y;
        s[b4 * 4 + 2] += (float)v4.z; s[b4 * 4 + 3] += (float)v4.w;
      }
    }
    _Float16* dst = &O[((size_t)h * 4096 + q) * 32 + d0];
    f16x8 o8;
    #pragma unroll
    for (int i = 0; i < 8; ++i) o8[i] = (_Float16)(s[i] * inv);
    *reinterpret_cast<f16x8*>(dst) = o8;
    #pragma unroll
    for (int i = 0; i < 8; ++i) o8[i] = (_Float16)(s[8 + i] * inv);
    *reinterpret_cast<f16x8*>(dst + 8) = o8;
  }
}

// ---------------- Kernel 3: output projection + bias (reads normalized O) ----------------
__global__ __launch_bounds__(512) void out_kernel(
    const _Float16* __restrict__ O, const float* __restrict__ wo,
    const float* __restrict__ bo, float* __restrict__ y)
{
  __shared__ __align__(16) float as[16 * 132];
  __shared__ __align__(16) float wsh[64 * 132];
  const int t = threadIdx.x;
  const int nb = blockIdx.x * 16;
  {
    int ch = t;
    #pragma unroll
    for (int i = 0; i < 4; ++i, ch += 512) {
      int r = ch >> 5, p = ch & 31;
      *reinterpret_cast<float4*>(&wsh[r * 132 + p * 4]) =
          *reinterpret_cast<const float4*>(&wo[r * 128 + p * 4]);
    }
  }
  {
    // 512 chunks of 4 d-values: one per thread.
    int r = t >> 5, p = t & 31;         // p in f16x4 units; h = p>>3
    int h = p >> 3, d4 = (p & 7) * 4;
    f16x4 o4 = *reinterpret_cast<const f16x4*>(
        &O[((size_t)h * 4096 + nb + r) * 32 + d4]);
    float4 s = {(float)o4.x, (float)o4.y, (float)o4.z, (float)o4.w};
    *reinterpret_cast<float4*>(&as[r * 132 + p * 4]) = s;
  }
  __syncthreads();
  const int oL = (t >> 4) * 2;
  const int n = t & 15;
  float acc[2] = {0.f, 0.f};
  for (int c = 0; c < 128; c += 4) {
    float4 a = *reinterpret_cast<const float4*>(&as[n * 132 + c]);
    #pragma unroll
    for (int i = 0; i < 2; ++i) {
      float4 wv = *reinterpret_cast<const float4*>(&wsh[(oL + i) * 132 + c]);
      acc[i] += wv.x * a.x + wv.y * a.y + wv.z * a.z + wv.w * a.w;
    }
  }
  #pragma unroll
  for (int i = 0; i < 2; ++i) {
    y[(size_t)(oL + i) * 4096 + nb + n] = acc[i] + bo[oL + i];
  }
}

extern "C" void kernel_launch(void* const* d_in, const int* in_sizes, int n_in,
                              void* d_out, int out_size, void* d_ws, size_t ws_size,
                              hipStream_t stream) {
  (void)in_sizes; (void)n_in; (void)out_size; (void)ws_size;
  const float* x     = (const float*)d_in[0];
  const float* w_qkv = (const float*)d_in[1];
  const float* w_out = (const float*)d_in[2];
  const float* b_out = (const float*)d_in[3];
  float* y = (float*)d_out;
  _Float16* qb = (_Float16*)d_ws;
  _Float16* kb = qb + 524288;
  _Float16* vb = kb + 524288;
  _Float16* Opart = vb + 524288;             // 8*4*4096*32 = 4,194,304 f16 (8 MB)
  _Float16* O     = Opart + 4194304;         // 4*4096*32   =   524,288 f16 (1 MB)
  float* lpart = (float*)(O + 524288);       // 8*4*4096    =   131,072 f32 (512 KB)
  unsigned int* cnt = (unsigned int*)(lpart + 131072);  // 64 u32

  hipMemsetAsync(cnt, 0, 64 * sizeof(unsigned int), stream);
  qkv_kernel<<<dim3(64, 12), 256, 0, stream>>>(x, w_qkv, qb, kb, vb);
  attn_kernel<<<dim3(8, 16, 4), 512, 0, stream>>>(qb, kb, vb, Opart, O, lpart, cnt, 4096 / 8);
  out_kernel<<<256, 512, 0, stream>>>(O, w_out, b_out, y);
}

// Round 9
// 98.754 us; speedup vs baseline: 2.4572x; 2.4572x over previous
//
#include <hip/hip_runtime.h>

// R16 = R13b verbatim (verified 97.79us): revert R15's fence-based combine
// (device-scope __threadfence per block forces L2 writeback -> +145us; same
// closed direction as R12's grid.sync). 3-kernel structure, f16 Opart.
//
// Workspace (~11.6 MB):
//   qb: [4][4096][32] f16 (pre-scaled by 32^-0.5 * log2e)   1 MB
//   kb: [4][4096][32] f16                                   1 MB
//   vb: [4][32][4096] f16                                   1 MB
//   Opart: [8ck][4h][4096][32] f16                          8 MB
//   lpart: [8ck][4h][4096] f32                              512 KB

typedef _Float16 f16x8 __attribute__((ext_vector_type(8)));
typedef _Float16 f16x4 __attribute__((ext_vector_type(4)));
typedef _Float16 f16x2v __attribute__((ext_vector_type(2)));
typedef __fp16 fp16x2n __attribute__((ext_vector_type(2)));   // builtin's native type
typedef float f32x4 __attribute__((ext_vector_type(4)));

static __device__ inline f16x4 pack4(float a, float b, float c, float d) {
  f16x4 r;
  r.x = (_Float16)a; r.y = (_Float16)b; r.z = (_Float16)c; r.w = (_Float16)d;
  return r;
}
static __device__ inline f16x4 pack4_rtz(float a, float b, float c, float d) {
  fp16x2n lo = __builtin_amdgcn_cvt_pkrtz(a, b);
  fp16x2n hi = __builtin_amdgcn_cvt_pkrtz(c, d);
  f16x4 r;
  r.x = (_Float16)lo.x; r.y = (_Float16)lo.y;
  r.z = (_Float16)hi.x; r.w = (_Float16)hi.y;
  return r;
}
static __device__ inline f16x2v pack2(float a, float b) {
  f16x2v r;
  r.x = (_Float16)a; r.y = (_Float16)b;
  return r;
}

// ---------------- Kernel 1: QKV projection ----------------
__global__ __launch_bounds__(256) void qkv_kernel(
    const float* __restrict__ x, const float* __restrict__ w,
    _Float16* __restrict__ qo, _Float16* __restrict__ ko, _Float16* __restrict__ vo)
{
  __shared__ __align__(16) float xs[64 * 68];
  __shared__ __align__(16) float wsb[32 * 68];
  const int t = threadIdx.x;
  const int n0 = blockIdx.x * 64;
  const int o0 = blockIdx.y * 32;
  #pragma unroll
  for (int i = 0; i < 4; ++i) {
    int ch = t + i * 256;
    int c = ch >> 4, p = ch & 15;
    *reinterpret_cast<float4*>(&xs[c * 68 + p * 4]) =
        *reinterpret_cast<const float4*>(&x[c * 4096 + n0 + p * 4]);
  }
  #pragma unroll
  for (int i = 0; i < 2; ++i) {
    int ch = t + i * 256;
    int o = ch >> 4, p = ch & 15;
    *reinterpret_cast<float4*>(&wsb[o * 68 + p * 4]) =
        *reinterpret_cast<const float4*>(&w[(o0 + o) * 64 + p * 4]);
  }
  __syncthreads();
  const int oL = (t >> 5) * 4;
  const int nL = (t & 31) * 2;
  float acc[4][2] = {};
  for (int c4 = 0; c4 < 64; c4 += 4) {
    float2 xa[4];
    #pragma unroll
    for (int k = 0; k < 4; ++k)
      xa[k] = *reinterpret_cast<const float2*>(&xs[(c4 + k) * 68 + nL]);
    #pragma unroll
    for (int i = 0; i < 4; ++i) {
      float4 wv = *reinterpret_cast<const float4*>(&wsb[(oL + i) * 68 + c4]);
      acc[i][0] += wv.x * xa[0].x + wv.y * xa[1].x + wv.z * xa[2].x + wv.w * xa[3].x;
      acc[i][1] += wv.x * xa[0].y + wv.y * xa[1].y + wv.z * xa[2].y + wv.w * xa[3].y;
    }
  }
  const float qs = 0.17677669529663689f * 1.4426950408889634f;  // 32^-.5 * log2e
  if (o0 < 128) {
    int ho = o0 >> 5;
    #pragma unroll
    for (int j = 0; j < 2; ++j) {
      int n = n0 + nL + j;
      *reinterpret_cast<f16x4*>(&qo[(ho * 4096 + n) * 32 + oL]) =
          pack4(acc[0][j] * qs, acc[1][j] * qs, acc[2][j] * qs, acc[3][j] * qs);
    }
  } else if (o0 < 256) {
    int ho = (o0 - 128) >> 5;
    #pragma unroll
    for (int j = 0; j < 2; ++j) {
      int n = n0 + nL + j;
      *reinterpret_cast<f16x4*>(&ko[(ho * 4096 + n) * 32 + oL]) =
          pack4(acc[0][j], acc[1][j], acc[2][j], acc[3][j]);
    }
  } else {
    #pragma unroll
    for (int i = 0; i < 4; ++i) {
      *reinterpret_cast<f16x2v*>(&vo[(size_t)(o0 - 256 + oL + i) * 4096 + n0 + nL]) =
          pack2(acc[i][0], acc[i][1]);
    }
  }
}

// ---------------- Kernel 2: flash attention, 8 waves/block, LDS K/V shared ----------------
// grid (8 chunks, 16 qblocks of 256, 4 heads); 8 waves/block, wave owns 32 q.
// Threads 0-255 stage K, threads 256-511 stage V.
__global__ __launch_bounds__(512, 4) void attn_kernel(
    const _Float16* __restrict__ qg, const _Float16* __restrict__ kg,
    const _Float16* __restrict__ vg, _Float16* __restrict__ Opart,
    float* __restrict__ lpart, int jlen)
{
  __shared__ __align__(16) _Float16 Ks[2][64 * 40];  // [j][d] stride 40
  __shared__ __align__(16) _Float16 Vs[2][32 * 72];  // [d][j] stride 72
  const int t = threadIdx.x;
  const int ck = blockIdx.x;
  const int qt = blockIdx.y;
  const int h  = blockIdx.z;
  const int w = t >> 6;
  const int lane = t & 63;
  const int m = lane & 15;
  const int quad = lane >> 4;
  const int qw = qt * 256 + w * 32;

  // Q fragments (B-operand of S^T): group g covers q = qw + g*16 + m
  f16x8 aq[2];
  #pragma unroll
  for (int g = 0; g < 2; ++g)
    aq[g] = *reinterpret_cast<const f16x8*>(
        &qg[(h * 4096 + qw + g * 16 + m) * 32 + quad * 8]);

  f32x4 acc[2][2];
  #pragma unroll
  for (int g = 0; g < 2; ++g) {
    acc[g][0] = f32x4{0.f, 0.f, 0.f, 0.f};
    acc[g][1] = f32x4{0.f, 0.f, 0.f, 0.f};
  }
  float ls[2] = {0.f, 0.f};

  const int jbeg = ck * jlen;
  const bool isK = (t < 256);
  const _Float16* gp;
  int ldsoff;
  if (isK) {
    int kr = t >> 2, ksg = t & 3;        // K staging: 64 rows x 4 x 16B
    gp = kg + (size_t)(h * 4096 + jbeg + kr) * 32 + ksg * 8;
    ldsoff = kr * 40 + ksg * 8;
  } else {
    int c = t - 256, vr = c >> 3, vsg = c & 7;  // V staging: 32 rows x 8 x 16B
    gp = vg + (size_t)(h * 32 + vr) * 4096 + jbeg + vsg * 8;
    ldsoff = vr * 72 + vsg * 8;
  }

  if (isK)
    *reinterpret_cast<uint4*>(&Ks[0][ldsoff]) = *reinterpret_cast<const uint4*>(gp);
  else
    *reinterpret_cast<uint4*>(&Vs[0][ldsoff]) = *reinterpret_cast<const uint4*>(gp);
  __syncthreads();

  for (int it = 0; it < jlen; it += 64) {
    const int buf = (it >> 6) & 1;
    if (it + 64 < jlen) {
      if (isK)
        *reinterpret_cast<uint4*>(&Ks[buf ^ 1][ldsoff]) =
            *reinterpret_cast<const uint4*>(gp + (size_t)(it + 64) * 32);
      else
        *reinterpret_cast<uint4*>(&Vs[buf ^ 1][ldsoff]) =
            *reinterpret_cast<const uint4*>(gp + (it + 64));
    }
    #pragma unroll
    for (int jt = 0; jt < 4; ++jt) {
      f16x8 kf = *reinterpret_cast<const f16x8*>(&Ks[buf][(jt * 16 + m) * 40 + quad * 8]);
      f16x4 vf0 = *reinterpret_cast<const f16x4*>(&Vs[buf][m * 72 + jt * 16 + quad * 4]);
      f16x4 vf1 = *reinterpret_cast<const f16x4*>(&Vs[buf][(16 + m) * 72 + jt * 16 + quad * 4]);
      f32x4 z = {0.f, 0.f, 0.f, 0.f};
      f32x4 sT[2];
      #pragma unroll
      for (int g = 0; g < 2; ++g)
        sT[g] = __builtin_amdgcn_mfma_f32_16x16x32_f16(kf, aq[g], z, 0, 0, 0);
      #pragma unroll
      for (int g = 0; g < 2; ++g) {
        float p0 = exp2f(sT[g][0]), p1 = exp2f(sT[g][1]);
        float p2 = exp2f(sT[g][2]), p3 = exp2f(sT[g][3]);
        ls[g] += (p0 + p1) + (p2 + p3);
        f16x4 p = pack4_rtz(p0, p1, p2, p3);   // A[m=q][k=quad*4+r]
        acc[g][0] = __builtin_amdgcn_mfma_f32_16x16x16f16(p, vf0, acc[g][0], 0, 0, 0);
        acc[g][1] = __builtin_amdgcn_mfma_f32_16x16x16f16(p, vf1, acc[g][1], 0, 0, 0);
      }
    }
    __syncthreads();
  }

  #pragma unroll
  for (int g = 0; g < 2; ++g) {
    ls[g] += __shfl_xor(ls[g], 16);
    ls[g] += __shfl_xor(ls[g], 32);
  }
  // O partials in f16: C-layout rows q_local = quad*4+r, col d = m
  const size_t cb = (size_t)(ck * 4 + h) * 4096;
  #pragma unroll
  for (int g = 0; g < 2; ++g) {
    #pragma unroll
    for (int dt = 0; dt < 2; ++dt) {
      #pragma unroll
      for (int r = 0; r < 4; ++r) {
        int q = qw + g * 16 + quad * 4 + r;
        Opart[(cb + q) * 32 + dt * 16 + m] = (_Float16)acc[g][dt][r];
      }
    }
  }
  if (quad == 0) {
    #pragma unroll
    for (int g = 0; g < 2; ++g)
      lpart[cb + qw + g * 16 + m] = ls[g];
  }
}

// ---------------- Kernel 3: combine partials + output projection + bias ----------------
__global__ __launch_bounds__(512) void out_kernel(
    const _Float16* __restrict__ Opart, const float* __restrict__ lpart,
    const float* __restrict__ wo, const float* __restrict__ bo,
    float* __restrict__ y)
{
  __shared__ __align__(16) float as[16 * 132];
  __shared__ __align__(16) float wsh[64 * 132];
  __shared__ float linv[64];          // [h][r]
  const int t = threadIdx.x;
  const int nb = blockIdx.x * 16;
  if (t < 64) {
    int h = t >> 4, r = t & 15;
    float s = 0.f;
    #pragma unroll
    for (int ck = 0; ck < 8; ++ck)
      s += lpart[(size_t)(ck * 4 + h) * 4096 + nb + r];
    linv[t] = 1.f / s;
  }
  {
    int ch = t;
    #pragma unroll
    for (int i = 0; i < 4; ++i, ch += 512) {
      int r = ch >> 5, p = ch & 31;
      *reinterpret_cast<float4*>(&wsh[r * 132 + p * 4]) =
          *reinterpret_cast<const float4*>(&wo[r * 128 + p * 4]);
    }
  }
  __syncthreads();
  {
    // 512 chunks of 4 d-values: one per thread.
    int r = t >> 5, p = t & 31;         // p in f16x4 units; h = p>>3
    int h = p >> 3, d4 = (p & 7) * 4;
    float sx = 0.f, sy = 0.f, sz = 0.f, sw = 0.f;
    #pragma unroll
    for (int ck = 0; ck < 8; ++ck) {
      f16x4 o4 = *reinterpret_cast<const f16x4*>(
          &Opart[((size_t)(ck * 4 + h) * 4096 + nb + r) * 32 + d4]);
      sx += (float)o4.x; sy += (float)o4.y; sz += (float)o4.z; sw += (float)o4.w;
    }
    float inv = linv[h * 16 + r];
    float4 s = {sx * inv, sy * inv, sz * inv, sw * inv};
    *reinterpret_cast<float4*>(&as[r * 132 + p * 4]) = s;
  }
  __syncthreads();
  const int oL = (t >> 4) * 2;
  const int n = t & 15;
  float acc[2] = {0.f, 0.f};
  for (int c = 0; c < 128; c += 4) {
    float4 a = *reinterpret_cast<const float4*>(&as[n * 132 + c]);
    #pragma unroll
    for (int i = 0; i < 2; ++i) {
      float4 wv = *reinterpret_cast<const float4*>(&wsh[(oL + i) * 132 + c]);
      acc[i] += wv.x * a.x + wv.y * a.y + wv.z * a.z + wv.w * a.w;
    }
  }
  #pragma unroll
  for (int i = 0; i < 2; ++i) {
    y[(size_t)(oL + i) * 4096 + nb + n] = acc[i] + bo[oL + i];
  }
}

extern "C" void kernel_launch(void* const* d_in, const int* in_sizes, int n_in,
                              void* d_out, int out_size, void* d_ws, size_t ws_size,
                              hipStream_t stream) {
  (void)in_sizes; (void)n_in; (void)out_size; (void)ws_size;
  const float* x     = (const float*)d_in[0];
  const float* w_qkv = (const float*)d_in[1];
  const float* w_out = (const float*)d_in[2];
  const float* b_out = (const float*)d_in[3];
  float* y = (float*)d_out;
  _Float16* qb = (_Float16*)d_ws;
  _Float16* kb = qb + 524288;
  _Float16* vb = kb + 524288;
  _Float16* Opart = vb + 524288;             // 8*4*4096*32 = 4,194,304 f16 (8 MB)
  float* lpart = (float*)(Opart + 4194304);  // 8*4*4096   =   131,072 f32

  qkv_kernel<<<dim3(64, 12), 256, 0, stream>>>(x, w_qkv, qb, kb, vb);
  attn_kernel<<<dim3(8, 16, 4), 512, 0, stream>>>(qb, kb, vb, Opart, lpart, 4096 / 8);
  out_kernel<<<256, 512, 0, stream>>>(Opart, lpart, w_out, b_out, y);
}